// Round 11
// baseline (37.965 us; speedup 1.0000x reference)
//
#include <hip/hip_runtime.h>

typedef float f32x4 __attribute__((ext_vector_type(4)));

#define NTILES  34104   // 8-position tiles: 25600+6400+1600+400+104
#define NWAVES  8192    // 2048 blocks * 4 waves (8 blocks/CU resident)
#define WWORDS  704     // 8*87 data + 8 flag words per wave slice

struct Tile {
    const float *cls, *bbx, *ctr;
    int img, HW, W, str, ksh, p0, valid;
    long obase;
};

__device__ __forceinline__ Tile decode(int gw,
    const float* cl0, const float* bb0, const float* ct0,
    const float* cl1, const float* bb1, const float* ct1,
    const float* cl2, const float* bb2, const float* ct2,
    const float* cl3, const float* bb3, const float* ct3,
    const float* cl4, const float* bb4, const float* ct4)
{
    Tile T; int wi;
    if (gw < 25600)      { T.cls=cl0;T.bbx=bb0;T.ctr=ct0;T.HW=25600;T.W=160;T.str=8;  T.ksh=4;T.obase=0;
                           T.img = gw / 3200;          wi = gw - T.img * 3200; }
    else if (gw < 32000) { T.cls=cl1;T.bbx=bb1;T.ctr=ct1;T.HW=6400; T.W=80; T.str=16; T.ksh=3;T.obase=17817600;
                           const int u = gw - 25600;   T.img = u / 800;  wi = u - T.img * 800; }
    else if (gw < 33600) { T.cls=cl2;T.bbx=bb2;T.ctr=ct2;T.HW=1600; T.W=40; T.str=32; T.ksh=2;T.obase=22272000;
                           const int u = gw - 32000;   T.img = u / 200;  wi = u - T.img * 200; }
    else if (gw < 34000) { T.cls=cl3;T.bbx=bb3;T.ctr=ct3;T.HW=400;  T.W=20; T.str=64; T.ksh=1;T.obase=23385600;
                           const int u = gw - 33600;   T.img = u / 50;   wi = u - T.img * 50; }
    else                 { T.cls=cl4;T.bbx=bb4;T.ctr=ct4;T.HW=100;  T.W=10; T.str=128;T.ksh=0;T.obase=23664000;
                           const int u = gw - 34000;   T.img = u / 13;   wi = u - T.img * 13; }
    T.p0 = wi * 8;
    T.valid = min(8, T.HW - T.p0);
    return T;
}

// Unconditional loads (clamped addresses) so the waitcnt pass can count
// outstanding loads exactly -> counted vmcnt, pipeline survives.
__device__ __forceinline__ void issue(const Tile& T, int cb, int q,
                                      float4& v0, float4& v1, float4& v2)
{
    const int qo = (4 * q < T.valid) ? 4 * q : 0;   // tail: duplicate quad 0
    const size_t po = (size_t)(T.p0 + qo);
    const float* a0 = T.cls + ((size_t)T.img * 80 + cb) * T.HW + po;
    v0 = *reinterpret_cast<const float4*>(a0);
    v1 = *reinterpret_cast<const float4*>(a0 + (size_t)32 * T.HW);
    const int c = 64 + ((cb < 21) ? cb : 20);       // clamp channel to 84
    const float* s = (c < 80) ? T.cls + ((size_t)T.img * 80 + c) * T.HW
                   : (c < 84) ? T.bbx + ((size_t)T.img * 4 + (c - 80)) * T.HW
                              : T.ctr + (size_t)T.img * T.HW;
    v2 = *reinterpret_cast<const float4*>(s + po);
}

__device__ __forceinline__ void process(const Tile& T, int lane, int cb, int q,
                                        float* wlds, float* wflag, float* __restrict__ out,
                                        const float4& v0, const float4& v1, const float4& v2)
{
    const bool pok = 4 * q < T.valid;

    float4 fm;
    fm.x = fmaxf(v0.x, v1.x); fm.y = fmaxf(v0.y, v1.y);
    fm.z = fmaxf(v0.z, v1.z); fm.w = fmaxf(v0.w, v1.w);
    if (cb < 16) {                       // channels 64..79 feed the max too
        fm.x = fmaxf(fm.x, v2.x); fm.y = fmaxf(fm.y, v2.y);
        fm.z = fmaxf(fm.z, v2.z); fm.w = fmaxf(fm.w, v2.w);
    }
    if (!pok) { fm.x = fm.y = fm.z = fm.w = -1e30f; }

    // reduce max over channel bits (lane bits 1..5); quad bit 0 preserved
    #pragma unroll
    for (int m = 2; m <= 32; m <<= 1) {
        fm.x = fmaxf(fm.x, __shfl_xor(fm.x, m));
        fm.y = fmaxf(fm.y, __shfl_xor(fm.y, m));
        fm.z = fmaxf(fm.z, __shfl_xor(fm.z, m));
        fm.w = fmaxf(fm.w, __shfl_xor(fm.w, m));
    }
    float4 mk;
    mk.x = (fm.x > 0.5f) ? 1.0f : 0.0f;
    mk.y = (fm.y > 0.5f) ? 1.0f : 0.0f;
    mk.z = (fm.z > 0.5f) ? 1.0f : 0.0f;
    mk.w = (fm.w > 0.5f) ? 1.0f : 0.0f;

    // transpose-write into wave-private slice, mask pre-applied (rows of 87)
    const int r0w = 4 * q * 87;
    if (pok) {
        wlds[r0w +   0 + 2 + cb]  = v0.x * mk.x;
        wlds[r0w +  87 + 2 + cb]  = v0.y * mk.y;
        wlds[r0w + 174 + 2 + cb]  = v0.z * mk.z;
        wlds[r0w + 261 + 2 + cb]  = v0.w * mk.w;
        wlds[r0w +   0 + 34 + cb] = v1.x * mk.x;
        wlds[r0w +  87 + 34 + cb] = v1.y * mk.y;
        wlds[r0w + 174 + 34 + cb] = v1.z * mk.z;
        wlds[r0w + 261 + 34 + cb] = v1.w * mk.w;
        if (cb < 21) {
            wlds[r0w +   0 + 66 + cb] = v2.x * mk.x;
            wlds[r0w +  87 + 66 + cb] = v2.y * mk.y;
            wlds[r0w + 174 + 66 + cb] = v2.z * mk.z;
            wlds[r0w + 261 + 66 + cb] = v2.w * mk.w;
        }
    }
    if (lane < 2) {                      // lane == q; publish this quad's masks
        f32x4 mo; mo.x = mk.x; mo.y = mk.y; mo.z = mk.z; mo.w = mk.w;
        *reinterpret_cast<f32x4*>(wflag + 4 * lane) = mo;
    }
    if (lane < 8) {                      // coords; in-wave ds RAW order is safe
        const float m = wflag[lane];
        const int pg = T.p0 + lane;
        const int tt = pg >> T.ksh;      // = pg / (W/10)
        const int y  = tt / 10;
        const int x  = pg - y * T.W;
        wlds[lane * 87 + 0] = (float)(x * T.str + (T.str >> 1)) * m;
        wlds[lane * 87 + 1] = (float)(y * T.str + (T.str >> 1)) * m;
    }

    // pure linear LDS -> global copy
    float* dst = out + T.obase + ((size_t)T.img * T.HW + T.p0) * 87;
    const int nw = T.valid * 87;         // 696 or 348, multiple of 4
    {
        const int w = 4 * lane;
        if (w < nw) *reinterpret_cast<f32x4*>(dst + w) = *reinterpret_cast<const f32x4*>(wlds + w);
    }
    {
        const int w = 4 * (lane + 64);
        if (w < nw) *reinterpret_cast<f32x4*>(dst + w) = *reinterpret_cast<const f32x4*>(wlds + w);
    }
    {
        const int w = 4 * (lane + 128);
        if (w < nw) *reinterpret_cast<f32x4*>(dst + w) = *reinterpret_cast<const f32x4*>(wlds + w);
    }
}

__global__ __launch_bounds__(256) void fcos_filter_kernel(
    const float* __restrict__ cl0, const float* __restrict__ bb0, const float* __restrict__ ct0,
    const float* __restrict__ cl1, const float* __restrict__ bb1, const float* __restrict__ ct1,
    const float* __restrict__ cl2, const float* __restrict__ bb2, const float* __restrict__ ct2,
    const float* __restrict__ cl3, const float* __restrict__ bb3, const float* __restrict__ ct3,
    const float* __restrict__ cl4, const float* __restrict__ bb4, const float* __restrict__ ct4,
    float* __restrict__ out)
{
    __shared__ float lds[4 * WWORDS];    // 11,264 B
    const int tid  = threadIdx.x;
    const int lane = tid & 63;
    float* wlds  = lds + (tid >> 6) * WWORDS;
    float* wflag = wlds + 696;
    const int cb = lane >> 1;
    const int q  = lane & 1;

    // wave-uniform tile index in SGPRs (keeps decode scalar, VGPRs low)
    int t = __builtin_amdgcn_readfirstlane((int)(blockIdx.x * 4) + (tid >> 6));

    Tile cur = decode(t, cl0,bb0,ct0, cl1,bb1,ct1, cl2,bb2,ct2, cl3,bb3,ct3, cl4,bb4,ct4);
    float4 a0, a1, a2;
    issue(cur, cb, q, a0, a1, a2);

    // 2-stage pipeline: next tile's loads in flight across current tile's process
    while (true) {
        const int tn = t + NWAVES;
        if (tn < NTILES) {
            Tile nxt = decode(tn, cl0,bb0,ct0, cl1,bb1,ct1, cl2,bb2,ct2, cl3,bb3,ct3, cl4,bb4,ct4);
            float4 b0, b1, b2;
            issue(nxt, cb, q, b0, b1, b2);
            process(cur, lane, cb, q, wlds, wflag, out, a0, a1, a2);
            cur = nxt; a0 = b0; a1 = b1; a2 = b2;
            t = tn;
        } else {
            process(cur, lane, cb, q, wlds, wflag, out, a0, a1, a2);
            break;
        }
    }
}

extern "C" void kernel_launch(void* const* d_in, const int* in_sizes, int n_in,
                              void* d_out, int out_size, void* d_ws, size_t ws_size,
                              hipStream_t stream) {
    (void)in_sizes; (void)n_in; (void)out_size; (void)d_ws; (void)ws_size;
    fcos_filter_kernel<<<2048, 256, 0, stream>>>(
        (const float*)d_in[0],  (const float*)d_in[1],  (const float*)d_in[2],
        (const float*)d_in[3],  (const float*)d_in[4],  (const float*)d_in[5],
        (const float*)d_in[6],  (const float*)d_in[7],  (const float*)d_in[8],
        (const float*)d_in[9],  (const float*)d_in[10], (const float*)d_in[11],
        (const float*)d_in[12], (const float*)d_in[13], (const float*)d_in[14],
        (float*)d_out);
}